// Round 6
// baseline (1042.489 us; speedup 1.0000x reference)
//
#include <hip/hip_runtime.h>
#include <hip/hip_bf16.h>

#define EW 640
#define EH 480
#define NVOX (2 * EH * EW)     // 614400 voxels
#define NWORDS (NVOX / 32)     // 19200 uint32 words = 76800 B bitmap
#define NCHUNK 16              // kept for layout compat (unused partials)

typedef float vf4 __attribute__((ext_vector_type(4)));

__device__ __forceinline__ int ev_idx(vf4 e) {
    // idx = x + W*y + W*H*((p+1)/2); exact in fp32 (all values < 2^24)
    float p01 = (e.w + 1.0f) * 0.5f;   // {-1,1} -> {0,1}
    return (int)(e.x + (float)EW * e.y + (float)(EW * EH) * p01);
}

// One thread per event; atomicOr directly into a global 76.8 KB bitmap.
// R3->R4 lesson: global atomics on an L2-resident region are ~free (8M
// contended atomicOr cost <5 us). Bitmap = 1200 lines (~150/XCD) -> stays
// hot in L2; HBM write traffic ~0 (vs R1's 630 MB partial-line thrash).
// No LDS => full 32 waves/CU for latency hiding on the 268 MB read stream.
__global__ void __launch_bounds__(256)
event_atomic_kernel(const vf4* __restrict__ events,
                    unsigned int* __restrict__ gbm, int n) {
    int i = blockIdx.x * 256 + threadIdx.x;
    if (i < n) {
        vf4 e = events[i];                       // coalesced 16 B/lane
        int x = ev_idx(e);
        atomicOr(&gbm[x >> 5], 1u << (x & 31));  // fire-and-forget, no stall
    }
}

// Bitmap -> floats via LDS staging so all float4 stores are fully coalesced.
// Block covers 256 words = 8192 floats. Writes every element: no d_out memset.
__global__ void __launch_bounds__(256)
expand_kernel(const unsigned int* __restrict__ gbm, float* __restrict__ out) {
    __shared__ unsigned int sbm[256];
    int w = blockIdx.x * 256 + threadIdx.x;
    sbm[threadIdx.x] = gbm[w];
    __syncthreads();

    vf4* out4 = (vf4*)out + (size_t)blockIdx.x * 2048;   // 2048 float4 / block
    #pragma unroll
    for (int q = 0; q < 8; ++q) {
        int f = q * 256 + threadIdx.x;        // local float4 index [0,2048)
        unsigned int wv = sbm[f >> 3];        // 8 lanes share a word: broadcast
        int sh = (f & 7) * 4;
        vf4 v;
        v.x = (wv >> (sh + 0)) & 1u ? 1.0f : 0.0f;
        v.y = (wv >> (sh + 1)) & 1u ? 1.0f : 0.0f;
        v.z = (wv >> (sh + 2)) & 1u ? 1.0f : 0.0f;
        v.w = (wv >> (sh + 3)) & 1u ? 1.0f : 0.0f;
        out4[f] = v;
    }
}

extern "C" void kernel_launch(void* const* d_in, const int* in_sizes, int n_in,
                              void* d_out, int out_size, void* d_ws, size_t ws_size,
                              hipStream_t stream) {
    const vf4* events = (const vf4*)d_in[0];
    float* out = (float*)d_out;
    int n = in_sizes[0] / 4;                   // in_sizes[0] = N*4 flat elems

    unsigned int* gbm = (unsigned int*)d_ws;   // 76.8 KB global bitmap

    // ws is re-poisoned to 0xAA each call — zero just the bitmap (76.8 KB).
    hipMemsetAsync(gbm, 0, NWORDS * sizeof(unsigned int), stream);

    event_atomic_kernel<<<(n + 255) / 256, 256, 0, stream>>>(events, gbm, n);
    expand_kernel<<<NWORDS / 256, 256, 0, stream>>>(gbm, out);
}

// Round 7
// 388.708 us; speedup vs baseline: 2.6819x; 2.6819x over previous
//
#include <hip/hip_runtime.h>
#include <hip/hip_bf16.h>

#define EW 640
#define EH 480
#define NVOX (2 * EH * EW)     // 614400 voxels = 0.6 MB byte bitmap

typedef float vf4 __attribute__((ext_vector_type(4)));

__device__ __forceinline__ int ev_idx(vf4 e) {
    // idx = x + W*y + W*H*((p+1)/2); exact in fp32 (all values < 2^24)
    float p01 = (e.w + 1.0f) * 0.5f;   // {-1,1} -> {0,1}
    return (int)(e.x + (float)EW * e.y + (float)(EW * EH) * p01);
}

// One thread per event; racy idempotent byte store into a 0.6 MB bitmap.
// R6 lesson: scattered global atomics go memory-side (~21 Gop/s) — never.
// R1 lesson: a 2.4 MB float scatter region thrashes L2 (630 MB writeback);
// a 0.6 MB byte region is 15% of each XCD L2 and nt event loads keep the
// 268 MB stream from evicting it -> writeback ~once. Cross-XCD byte races
// merge correctly at writeback (byte dirty masks); expand is a separate
// kernel after the dispatch-boundary flush, so no stale-read hazard.
__global__ void __launch_bounds__(256)
event_scatter_byte_kernel(const vf4* __restrict__ events,
                          unsigned char* __restrict__ bm, int n) {
    int i = blockIdx.x * 256 + threadIdx.x;
    if (i < n) {
        vf4 e = __builtin_nontemporal_load(events + i);   // 16 B/lane, nt
        int x = ev_idx(e);
        bm[x] = (unsigned char)1;
    }
}

// Byte bitmap -> float output. Thread t reads 4 bytes (coalesced dword) and
// writes one float4 (16 B/lane, fully coalesced). Writes every element:
// no d_out memset needed. 153,600 threads.
__global__ void __launch_bounds__(256)
expand_kernel(const unsigned int* __restrict__ bm4, float* __restrict__ out) {
    int t = blockIdx.x * 256 + threadIdx.x;   // [0, NVOX/4)
    unsigned int b = bm4[t];
    vf4 v;
    v.x = (b & 0x000000ffu) ? 1.0f : 0.0f;
    v.y = (b & 0x0000ff00u) ? 1.0f : 0.0f;
    v.z = (b & 0x00ff0000u) ? 1.0f : 0.0f;
    v.w = (b & 0xff000000u) ? 1.0f : 0.0f;
    ((vf4*)out)[t] = v;
}

extern "C" void kernel_launch(void* const* d_in, const int* in_sizes, int n_in,
                              void* d_out, int out_size, void* d_ws, size_t ws_size,
                              hipStream_t stream) {
    const vf4* events = (const vf4*)d_in[0];
    float* out = (float*)d_out;
    int n = in_sizes[0] / 4;                   // in_sizes[0] = N*4 flat elems

    unsigned char* bm = (unsigned char*)d_ws;  // 0.6 MB byte bitmap

    // ws is re-poisoned to 0xAA each call — zero the bitmap (~1-2 us).
    hipMemsetAsync(bm, 0, NVOX, stream);

    event_scatter_byte_kernel<<<(n + 255) / 256, 256, 0, stream>>>(events, bm, n);
    expand_kernel<<<NVOX / 4 / 256, 256, 0, stream>>>((const unsigned int*)bm, out);
}

// Round 8
// 366.485 us; speedup vs baseline: 2.8446x; 1.0606x over previous
//
#include <hip/hip_runtime.h>
#include <hip/hip_bf16.h>

#define EW 640
#define EH 480
#define NVOX (2 * EH * EW)     // 614400 voxels
#define NWORDS (NVOX / 32)     // 19200 uint32 words = 76800 B bitmap
#define BLKA 1024              // stage-1 block (16 waves)
#define NBLK_A 512             // stage-1 grid -> 2 blocks/CU resident

typedef float vf4 __attribute__((ext_vector_type(4)));

__device__ __forceinline__ int ev_idx(vf4 e) {
    // idx = x + W*y + W*H*((p+1)/2); exact in fp32 (all values < 2^24)
    float p01 = (e.w + 1.0f) * 0.5f;   // {-1,1} -> {0,1}
    return (int)(e.x + (float)EW * e.y + (float)(EW * EH) * p01);
}

// Stage 1: per-block full-voxel-space bit bitmap in LDS (76.8 KB), TWO blocks
// resident per CU => 32 waves/CU (R3/R4/R5 all ran 16; per-CU BW was pinned at
// ~3.9 B/cyc ~= MSHR-cap x latency — doubling resident waves is the one lever
// not yet pulled). Merge tail: aggregated wave-contiguous global atomicOr
// (R3-measured cheap, ~15 us for 8M ops; unlike R6's scattered atomics).
__global__ void __launch_bounds__(BLKA, 8)   // 8 waves/EU => 2 blocks/CU
event_bitmap_kernel(const vf4* __restrict__ events,
                    unsigned int* __restrict__ gbm, int n) {
    __shared__ unsigned int bm[NWORDS];
    for (int w = threadIdx.x; w < NWORDS; w += BLKA) bm[w] = 0u;
    __syncthreads();

    const int nth = gridDim.x * BLKA;   // 524288 threads
    int i = blockIdx.x * BLKA + threadIdx.x;
    for (; i + 3 * nth < n; i += 4 * nth) {
        vf4 e0 = events[i];
        vf4 e1 = events[i + nth];
        vf4 e2 = events[i + 2 * nth];
        vf4 e3 = events[i + 3 * nth];
        int x0 = ev_idx(e0), x1 = ev_idx(e1), x2 = ev_idx(e2), x3 = ev_idx(e3);
        atomicOr(&bm[x0 >> 5], 1u << (x0 & 31));
        atomicOr(&bm[x1 >> 5], 1u << (x1 & 31));
        atomicOr(&bm[x2 >> 5], 1u << (x2 & 31));
        atomicOr(&bm[x3 >> 5], 1u << (x3 & 31));
    }
    for (; i < n; i += nth) {
        vf4 e = events[i];
        int x = ev_idx(e);
        atomicOr(&bm[x >> 5], 1u << (x & 31));
    }
    __syncthreads();

    // Aggregated merge: consecutive lanes hit consecutive words (line-batched
    // at L2). Skip zero words (~18% at 512 blocks).
    for (int w = threadIdx.x; w < NWORDS; w += BLKA) {
        unsigned int v = bm[w];
        if (v) atomicOr(&gbm[w], v);
    }
}

// Bit bitmap -> float output. Thread t handles one float4; 8 lanes share one
// bitmap word (L1 broadcast). 600 blocks; writes every element of d_out.
__global__ void __launch_bounds__(256)
expand_kernel(const unsigned int* __restrict__ gbm, float* __restrict__ out) {
    int t = blockIdx.x * 256 + threadIdx.x;   // [0, NVOX/4)
    unsigned int wv = gbm[t >> 3];
    int sh = (t & 7) * 4;
    vf4 v;
    v.x = (wv >> (sh + 0)) & 1u ? 1.0f : 0.0f;
    v.y = (wv >> (sh + 1)) & 1u ? 1.0f : 0.0f;
    v.z = (wv >> (sh + 2)) & 1u ? 1.0f : 0.0f;
    v.w = (wv >> (sh + 3)) & 1u ? 1.0f : 0.0f;
    ((vf4*)out)[t] = v;
}

extern "C" void kernel_launch(void* const* d_in, const int* in_sizes, int n_in,
                              void* d_out, int out_size, void* d_ws, size_t ws_size,
                              hipStream_t stream) {
    const vf4* events = (const vf4*)d_in[0];
    float* out = (float*)d_out;
    int n = in_sizes[0] / 4;                   // in_sizes[0] = N*4 flat elems

    unsigned int* gbm = (unsigned int*)d_ws;   // 76.8 KB global bitmap

    // ws is re-poisoned to 0xAA each call — zero the bitmap (~1 us).
    hipMemsetAsync(gbm, 0, NWORDS * sizeof(unsigned int), stream);

    event_bitmap_kernel<<<NBLK_A, BLKA, 0, stream>>>(events, gbm, n);
    expand_kernel<<<NVOX / 4 / 256, 256, 0, stream>>>(gbm, out);
}